// Round 20
// baseline (245.829 us; speedup 1.0000x reference)
//
#include <hip/hip_runtime.h>
#include <hip/hip_bf16.h>
#include <hip/hip_fp16.h>
#include <math.h>

// ---------------------------------------------------------------------------
// GCN: 3x gcn_conv(relu) -> tri-pool per graph -> MLP head -> sigmoid
// GEMMs on matrix cores (fp16 in, fp32 acc). Node features feature-BLOCKED:
// h[fb][v][32] (fb=0..3; 64B rows = 1 cache line); aggregation blocks pinned
// to XCD (fb = blockIdx&3) gather a 3.2MB slice (per-XCD L2 resident).
// agg: lane owns 8 feats (16B f16x8), 16 nodes/wave; block's edge-index
// segment staged into LDS; gathered rows summed via packed-f16 pairwise
// tree with fp32 master accumulator. CSR build: 8 dst-range queues
// (64B-aligned, sentinel-padded; line-padded counters), split LDS
// histograms (+ per-range edge totals), per-range fused scan (rowoff/
// cursor/dv in ONE kernel), XCD-pinned fill. Pool fused into MLP head.
// No hipMemsetAsync. 12 dispatches total.
// ---------------------------------------------------------------------------

typedef _Float16 f16;
typedef _Float16 f16x2 __attribute__((ext_vector_type(2)));
typedef _Float16 f16x4 __attribute__((ext_vector_type(4)));
typedef _Float16 f16x8 __attribute__((ext_vector_type(8)));
typedef float f32x4 __attribute__((ext_vector_type(4)));

#define NR 8          // dst ranges (one per XCD)
#define NSPLIT 32     // queue splits in fill pass
#define DSPLIT 16     // queue splits in deg-hist pass
#define QCAP 200000   // per-range queue capacity (valid ~100k + pad ~12k)
#define BSZ_MAX 6272  // max nodes per range (50000/8 = 6250, rounded up)
#define QPAD 16       // qcnt stride in ints (64B line per counter)
#define EPB 1024      // edges per block in bucket pass
#define ECAP 4096     // LDS edge-index cache per agg block (64 nodes)
#define SENTINEL 0xFFFFFFFFu

__device__ inline int wave_incl_scan(int v, int lane) {
    #pragma unroll
    for (int off = 1; off < 64; off <<= 1) {
        int nv = __shfl_up(v, off, 64);
        if (lane >= off) v += nv;
    }
    return v;
}

// CSR pass A: bucket edges into NR dst-range queues (packed dst<<16|src).
// Also zeros deg[]. 1024 edges/block (int4), ballot-aggregated LDS counters,
// ONE global atomicAdd per (block, range) on a line-padded counter.
__global__ __launch_bounds__(256) void bucket_edges(
    const int* __restrict__ src, const int* __restrict__ dst, int E, int bsz,
    int N, int* __restrict__ deg, int* __restrict__ qcnt,
    unsigned* __restrict__ q) {
    __shared__ int lcnt[NR];
    __shared__ int lbase[NR];
    const int t = threadIdx.x;
    const int lane = t & 63;

    // zero deg (50k ints over ~782 blocks: one strided pass)
    for (int i = blockIdx.x * 256 + t; i < N; i += gridDim.x * 256) deg[i] = 0;

    if (t < NR) lcnt[t] = 0;
    __syncthreads();

    const int e0 = blockIdx.x * EPB + t * 4;
    int  rj[4];
    int  lp[4];
    unsigned pk[4];
    if (e0 + 4 <= E) {
        int4 d4 = *(const int4*)(dst + e0);
        int4 s4 = *(const int4*)(src + e0);
        rj[0] = d4.x / bsz; pk[0] = ((unsigned)d4.x << 16) | (unsigned)s4.x;
        rj[1] = d4.y / bsz; pk[1] = ((unsigned)d4.y << 16) | (unsigned)s4.y;
        rj[2] = d4.z / bsz; pk[2] = ((unsigned)d4.z << 16) | (unsigned)s4.z;
        rj[3] = d4.w / bsz; pk[3] = ((unsigned)d4.w << 16) | (unsigned)s4.w;
    } else {
        #pragma unroll
        for (int j = 0; j < 4; ++j) {
            int e = e0 + j;
            if (e < E) {
                int d = dst[e];
                rj[j] = d / bsz;
                pk[j] = ((unsigned)d << 16) | (unsigned)src[e];
            } else rj[j] = -1;
        }
    }

    #pragma unroll
    for (int j = 0; j < 4; ++j) {
        #pragma unroll
        for (int rr = 0; rr < NR; ++rr) {
            bool mine = (rj[j] == rr);
            unsigned long long m = __ballot(mine);
            if (m) {
                int leader = __ffsll((long long)m) - 1;
                int base = 0;
                if (lane == leader) base = atomicAdd(&lcnt[rr], __popcll(m));
                base = __shfl(base, leader);
                if (mine) lp[j] = base + __popcll(m & ((1ull << lane) - 1ull));
            }
        }
    }
    __syncthreads();
    if (t < NR) {
        int padded = (lcnt[t] + 15) & ~15;
        lbase[t] = atomicAdd(&qcnt[t * QPAD], padded);  // padded: own 64B line
    }
    __syncthreads();
    #pragma unroll
    for (int j = 0; j < 4; ++j) {
        if (rj[j] >= 0) {
            int pos = lbase[rj[j]] + lp[j];
            if (pos < QCAP) q[(size_t)rj[j] * QCAP + pos] = pk[j];
        }
    }
    if (t < NR) {
        int base = lbase[t], c = lcnt[t], pad = (c + 15) & ~15;
        for (int i = c; i < pad; ++i)
            if (base + i < QCAP) q[(size_t)t * QCAP + base + i] = SENTINEL;
    }
}

// CSR pass B1: split per-range degree histograms (grid = NR * DSPLIT).
// Also accumulates each range's TRUE edge total into rtot[r] (one atomic
// per block) for the fused per-range scan.
__global__ __launch_bounds__(256) void deg_hist_split(
    const int* __restrict__ qcnt, const unsigned* __restrict__ q,
    int bsz, int N, int* __restrict__ deg, int* __restrict__ rtot) {
    __shared__ int hist[BSZ_MAX];
    __shared__ int csum[4];
    const int r = blockIdx.x & (NR - 1);
    const int sp = blockIdx.x >> 3;
    const int lo = r * bsz;
    const int hi = min(lo + bsz, N);
    const int span = hi - lo;
    const int t = threadIdx.x;
    const int lane = t & 63, wid = t >> 6;
    for (int i = t; i < span; i += 256) hist[i] = 0;
    __syncthreads();
    const int qn = min(qcnt[r * QPAD], QCAP);
    const int i0 = (int)((long long)qn * sp / DSPLIT);
    const int i1 = (int)((long long)qn * (sp + 1) / DSPLIT);
    const unsigned* qr = q + (size_t)r * QCAP;
    int cnt = 0;
    for (int i = i0 + t; i < i1; i += 256) {
        unsigned u = qr[i];
        if (u != SENTINEL) {
            atomicAdd(&hist[(int)(u >> 16) - lo], 1);
            ++cnt;
        }
    }
    __syncthreads();
    for (int i = t; i < span; i += 256) {
        int c = hist[i];
        if (c) atomicAdd(&deg[lo + i], c);
    }
    // block-reduce cnt -> rtot[r]
    #pragma unroll
    for (int off = 32; off > 0; off >>= 1) cnt += __shfl_down(cnt, off, 64);
    if (lane == 0) csum[wid] = cnt;
    __syncthreads();
    if (t == 0) atomicAdd(&rtot[r], csum[0] + csum[1] + csum[2] + csum[3]);
}

// CSR pass B2 (fused): per-range exclusive scan of deg -> rowoff + cursor,
// and dv. Grid = NR blocks x 1024 threads; block r scans its 6250-node span
// with base = sum(rtot[0..r-1]). Last block writes rowoff[N].
__global__ __launch_bounds__(1024) void range_scan(
    const int* __restrict__ deg, const int* __restrict__ rtot,
    int bsz, int N, int* __restrict__ rowoff, int* __restrict__ cursor,
    float* __restrict__ dv) {
    __shared__ int wsum[16];
    __shared__ int carry_s;
    const int r = blockIdx.x;
    const int lo = r * bsz;
    const int hi = min(lo + bsz, N);
    const int t = threadIdx.x;
    const int lane = t & 63, wid = t >> 6;

    if (t == 0) {
        int base = 0;
        for (int j = 0; j < r; ++j) base += rtot[j];
        carry_s = base;
    }
    __syncthreads();

    for (int i0 = lo; i0 < hi; i0 += 1024) {
        int i = i0 + t;
        int v = (i < hi) ? deg[i] : 0;
        if (i < hi) dv[i] = 1.0f / sqrtf((float)v + 1.0f);
        int isc = wave_incl_scan(v, lane);
        if (lane == 63) wsum[wid] = isc;
        __syncthreads();
        int carry = carry_s;
        int wb = 0;
        for (int w = 0; w < wid; ++w) wb += wsum[w];
        int tot = 0;
        for (int w = 0; w < 16; ++w) tot += wsum[w];
        int ex = carry + wb + isc - v;
        if (i < hi) { rowoff[i] = ex; cursor[i] = ex; }
        __syncthreads();
        if (t == 0) carry_s = carry + tot;
        __syncthreads();
    }
    if (r == NR - 1 && t == 0) rowoff[N] = carry_s;
}

// CSR pass B3: drain queue r = blockIdx&7 (XCD-pinned) -> colsrc scatter
// writes for range r stay in ONE L2.
__global__ __launch_bounds__(256) void fill_from_buckets(
    const int* __restrict__ qcnt, const unsigned* __restrict__ q,
    int* __restrict__ cursor, unsigned short* __restrict__ colsrc) {
    const int r = blockIdx.x & (NR - 1);
    const int sp = blockIdx.x >> 3;
    const int n = min(qcnt[r * QPAD], QCAP);
    const int i0 = (int)((long long)n * sp / NSPLIT);
    const int i1 = (int)((long long)n * (sp + 1) / NSPLIT);
    for (int i = i0 + threadIdx.x; i < i1; i += 256) {
        unsigned u = q[(size_t)r * QCAP + i];
        if (u == SENTINEL) continue;
        int d = u >> 16;
        int p = atomicAdd(&cursor[d], 1);
        colsrc[p] = (unsigned short)(u & 0xffffu);
    }
}

// Fused setup (launched FIRST): blocks 0..63 -> wcast; block 0 also zeros
// qcnt + rtot; blocks 64.. -> goff[g] = lower_bound(batch, g).
__global__ __launch_bounds__(256) void setup_misc(
    const float* __restrict__ W1, const float* __restrict__ W2,
    f16* __restrict__ Wt1, f16* __restrict__ Wt2,
    const int* __restrict__ batch, int N, int G, int* __restrict__ goff,
    int* __restrict__ qcnt) {
    const int b = blockIdx.x;
    if (b < 64) {
        if (b == 0 && threadIdx.x < NR * QPAD + NR) qcnt[threadIdx.x] = 0;
        int idx = b * 256 + threadIdx.x;  // 0..16383
        int n = idx >> 7, k = idx & 127;
        Wt1[idx] = (f16)W1[k * 128 + n];
        Wt2[idx] = (f16)W2[k * 128 + n];
    } else {
        int g = (b - 64) * 256 + threadIdx.x;
        if (g > G) return;
        int lo = 0, hi = N;
        while (lo < hi) {
            int mid = (lo + hi) >> 1;
            if (batch[mid] < g) lo = mid + 1; else hi = mid;
        }
        goff[g] = lo;
    }
}

// out[fb][m][32] = fp16((A[m][:] @ W) * dv[m])
// F32IN: A row-major fp32 [M][128] (input x); else blocked fp16 [fb][m][32].
// MFMA 16x16x32_f16, D[n][m]: lane's 4 acc regs = 4 consecutive n at one m.
template <bool F32IN>
__global__ __launch_bounds__(256) void gemm_mfma(
    const void* __restrict__ Ain, const f16* __restrict__ Wt,
    const float* __restrict__ dv, f16* __restrict__ out, int M) {
    const int lane = threadIdx.x & 63;
    const int w = threadIdx.x >> 6;
    const int wc = w & 1;
    const int wr = w >> 1;
    const int l15 = lane & 15;
    const int lg = lane >> 4;  // 0..3

    // Hoist Wt fragments (MFMA A-operand): A_op[n][k], n = l15, k = lg*8+j
    f16x8 wf[4][4];  // [nt][kb]
    #pragma unroll
    for (int nt = 0; nt < 4; ++nt) {
        const f16* wp = Wt + (size_t)(wc * 64 + nt * 16 + l15) * 128 + lg * 8;
        #pragma unroll
        for (int kb = 0; kb < 4; ++kb)
            wf[nt][kb] = *(const f16x8*)(wp + kb * 32);
    }

    #pragma unroll
    for (int step = 0; step < 2; ++step) {
        const int m = blockIdx.x * 64 + step * 32 + wr * 16 + l15;
        const int mc = min(m, M - 1);
        // B-operand: k = kb*32 + lg*8 + j  ->  block kb, offset lg*8
        f16x8 af[4];
        if constexpr (F32IN) {
            const float* ap = (const float*)Ain + (size_t)mc * 128 + lg * 8;
            #pragma unroll
            for (int kb = 0; kb < 4; ++kb) {
                float4 a = *(const float4*)(ap + kb * 32);
                float4 b = *(const float4*)(ap + kb * 32 + 4);
                f16x8 o;
                o[0] = (f16)a.x; o[1] = (f16)a.y; o[2] = (f16)a.z; o[3] = (f16)a.w;
                o[4] = (f16)b.x; o[5] = (f16)b.y; o[6] = (f16)b.z; o[7] = (f16)b.w;
                af[kb] = o;
            }
        } else {
            const f16* A = (const f16*)Ain;
            #pragma unroll
            for (int kb = 0; kb < 4; ++kb)
                af[kb] = *(const f16x8*)(A + ((size_t)kb * M + mc) * 32 + lg * 8);
        }
        const float d = dv[mc];
        #pragma unroll
        for (int nt = 0; nt < 4; ++nt) {
            f32x4 acc = {0.f, 0.f, 0.f, 0.f};
            #pragma unroll
            for (int kb = 0; kb < 4; ++kb)
                acc = __builtin_amdgcn_mfma_f32_16x16x32_f16(wf[nt][kb], af[kb], acc, 0, 0, 0);
            if (m < M) {
                // n = wc*64 + nt*16 + lg*4 + j -> fb = wc*2+(nt>>1), off = (nt&1)*16+lg*4
                f16x4 o;
                o[0] = (f16)(acc[0] * d);
                o[1] = (f16)(acc[1] * d);
                o[2] = (f16)(acc[2] * d);
                o[3] = (f16)(acc[3] * d);
                *(f16x4*)(out + ((size_t)(wc * 2 + (nt >> 1)) * M + m) * 32
                          + (nt & 1) * 16 + lg * 4) = o;
            }
        }
    }
}

// Feature-blocked aggregation, 4 fb x 32 feats (64B rows). Block handles
// fb = blockIdx&3 (XCD-pinned slice, L2-resident) and 64 nodes; edge-index
// segment staged in LDS. Wave = 16 node-slots x 4 lanes; lane owns 8 feats
// (f16x8, 16B). Gathered rows reduced via packed-f16 pairwise tree into a
// fp32 master accumulator once per 8-edge group.
__global__ __launch_bounds__(256) void agg_relu_b(
    const f16* __restrict__ hs, const float* __restrict__ dv,
    const float* __restrict__ bias, const int* __restrict__ rowoff,
    const unsigned short* __restrict__ colsrc, f16* __restrict__ out, int N) {
    __shared__ unsigned short ecache[ECAP];
    const int fb = blockIdx.x & 3;
    const int chunk = blockIdx.x >> 2;
    const int t = threadIdx.x;
    const int lane = t & 63;
    const int wav = t >> 6;
    const int sl = lane & 3;       // feature octet within row
    const int slot = lane >> 2;    // node slot within wave (16)
    const int vb0 = chunk * 64;
    const int v = vb0 + wav * 16 + slot;

    // stage the block's edge-index segment (all threads participate)
    const int vend = min(vb0 + 64, N);
    const int E0 = rowoff[vb0];
    const int E1 = rowoff[vend];
    const int nE = E1 - E0;
    const bool staged = (nE <= ECAP);
    if (staged) {
        for (int i = t; i < nE; i += 256) ecache[i] = colsrc[E0 + i];
    }
    __syncthreads();

    if (v >= N) return;

    const f16* slice = hs + (size_t)fb * N * 32;
    f16x8 h0 = *(const f16x8*)(slice + (size_t)v * 32 + sl * 8);
    float a0 = (float)h0[0], a1 = (float)h0[1], a2 = (float)h0[2], a3 = (float)h0[3];
    float a4 = (float)h0[4], a5 = (float)h0[5], a6 = (float)h0[6], a7 = (float)h0[7];

    const int e0 = rowoff[v], e1 = rowoff[v + 1];
    if (staged) {
        int eiter = e0 - E0;
        const int ee = e1 - E0;
        for (; eiter + 8 <= ee; eiter += 8) {
            int s[8];
            #pragma unroll
            for (int j = 0; j < 8; ++j) s[j] = ecache[eiter + j];
            f16x8 m[8];
            #pragma unroll
            for (int j = 0; j < 8; ++j)
                m[j] = *(const f16x8*)(slice + (size_t)s[j] * 32 + sl * 8);
            f16x8 t01 = m[0] + m[1];
            f16x8 t23 = m[2] + m[3];
            f16x8 t45 = m[4] + m[5];
            f16x8 t67 = m[6] + m[7];
            f16x8 tt = (t01 + t23) + (t45 + t67);
            a0 += (float)tt[0]; a1 += (float)tt[1];
            a2 += (float)tt[2]; a3 += (float)tt[3];
            a4 += (float)tt[4]; a5 += (float)tt[5];
            a6 += (float)tt[6]; a7 += (float)tt[7];
        }
        for (; eiter < ee; ++eiter) {
            int s = ecache[eiter];
            f16x8 mm = *(const f16x8*)(slice + (size_t)s * 32 + sl * 8);
            a0 += (float)mm[0]; a1 += (float)mm[1];
            a2 += (float)mm[2]; a3 += (float)mm[3];
            a4 += (float)mm[4]; a5 += (float)mm[5];
            a6 += (float)mm[6]; a7 += (float)mm[7];
        }
    } else {
        int e = e0;
        for (; e + 8 <= e1; e += 8) {
            int s[8];
            #pragma unroll
            for (int j = 0; j < 8; ++j) s[j] = colsrc[e + j];
            f16x8 m[8];
            #pragma unroll
            for (int j = 0; j < 8; ++j)
                m[j] = *(const f16x8*)(slice + (size_t)s[j] * 32 + sl * 8);
            f16x8 t01 = m[0] + m[1];
            f16x8 t23 = m[2] + m[3];
            f16x8 t45 = m[4] + m[5];
            f16x8 t67 = m[6] + m[7];
            f16x8 tt = (t01 + t23) + (t45 + t67);
            a0 += (float)tt[0]; a1 += (float)tt[1];
            a2 += (float)tt[2]; a3 += (float)tt[3];
            a4 += (float)tt[4]; a5 += (float)tt[5];
            a6 += (float)tt[6]; a7 += (float)tt[7];
        }
        for (; e < e1; ++e) {
            int s = colsrc[e];
            f16x8 mm = *(const f16x8*)(slice + (size_t)s * 32 + sl * 8);
            a0 += (float)mm[0]; a1 += (float)mm[1];
            a2 += (float)mm[2]; a3 += (float)mm[3];
            a4 += (float)mm[4]; a5 += (float)mm[5];
            a6 += (float)mm[6]; a7 += (float)mm[7];
        }
    }

    float d = dv[v];
    const float* bp = bias + fb * 32 + sl * 8;
    float4 b0 = *(const float4*)bp;
    float4 b1 = *(const float4*)(bp + 4);
    f16x8 o;
    o[0] = (f16)fmaxf(fmaf(d, a0, b0.x), 0.0f);
    o[1] = (f16)fmaxf(fmaf(d, a1, b0.y), 0.0f);
    o[2] = (f16)fmaxf(fmaf(d, a2, b0.z), 0.0f);
    o[3] = (f16)fmaxf(fmaf(d, a3, b0.w), 0.0f);
    o[4] = (f16)fmaxf(fmaf(d, a4, b1.x), 0.0f);
    o[5] = (f16)fmaxf(fmaf(d, a5, b1.y), 0.0f);
    o[6] = (f16)fmaxf(fmaf(d, a6, b1.z), 0.0f);
    o[7] = (f16)fmaxf(fmaf(d, a7, b1.w), 0.0f);
    *(f16x8*)(out + ((size_t)fb * N + v) * 32 + sl * 8) = o;
}

// Fused tri-pool + MLP head. One block (384 threads) per graph.
__global__ __launch_bounds__(384) void pool_mlp(
    const f16* __restrict__ h, const int* __restrict__ goff, int N,
    const float* __restrict__ lw1, const float* __restrict__ lb1,
    const float* __restrict__ lw2, const float* __restrict__ lb2,
    const float* __restrict__ lw3, const float* __restrict__ lb3,
    float* __restrict__ out) {
    __shared__ float psum[3][128];
    __shared__ float pmax[3][128];
    __shared__ float gin[384];
    __shared__ float h1[384];
    __shared__ float red[384];
    const int g = blockIdx.x, t = threadIdx.x;
    const int s = goff[g], e = goff[g + 1];

    {   // pool: group c = t>>7 strides the node range for feature f = t&127
        const int c = t >> 7, f = t & 127;
        const int fb = f >> 5, off = f & 31;
        const f16* slice = h + ((size_t)fb * N) * 32 + off;
        float sum = 0.0f, mx = 0.0f;  // h >= 0 post-relu
        for (int v = s + c; v < e; v += 3) {
            float val = (float)slice[(size_t)v * 32];
            sum += val;
            mx = fmaxf(mx, val);
        }
        psum[c][f] = sum;
        pmax[c][f] = mx;
    }
    __syncthreads();
    if (t < 128) {
        float ts = psum[0][t] + psum[1][t] + psum[2][t];
        float tm = fmaxf(fmaxf(pmax[0][t], pmax[1][t]), pmax[2][t]);
        float cnt = (float)(e - s);
        gin[t]       = ts / fmaxf(cnt, 1.0f);  // pmean (empty graph -> 0)
        gin[128 + t] = tm;                     // pmax
        gin[256 + t] = ts;                     // psum
    }
    __syncthreads();

    {   // layer 1: h1[t] = relu(lb1[t] + sum_i gin[i] * lw1[i][t])
        const float* wp = lw1 + t;
        float a0 = 0.f, a1 = 0.f, a2 = 0.f, a3 = 0.f;
        for (int i = 0; i < 384; i += 4) {
            a0 = fmaf(gin[i],     wp[(size_t)i * 384],        a0);
            a1 = fmaf(gin[i + 1], wp[(size_t)(i + 1) * 384],  a1);
            a2 = fmaf(gin[i + 2], wp[(size_t)(i + 2) * 384],  a2);
            a3 = fmaf(gin[i + 3], wp[(size_t)(i + 3) * 384],  a3);
        }
        h1[t] = fmaxf(lb1[t] + (a0 + a1) + (a2 + a3), 0.0f);
    }
    __syncthreads();

    {   // layer 2: partial over k-chunk (t>>7) for col (t&127)
        const int jj = t & 127, chunk = t >> 7;
        const float* wp = lw2 + (size_t)chunk * 128 * 128 + jj;
        const float* hp = h1 + chunk * 128;
        float a0 = 0.f, a1 = 0.f, a2 = 0.f, a3 = 0.f;
        for (int i = 0; i < 128; i += 4) {
            a0 = fmaf(hp[i],     wp[(size_t)i * 128],       a0);
            a1 = fmaf(hp[i + 1], wp[(size_t)(i + 1) * 128], a1);
            a2 = fmaf(hp[i + 2], wp[(size_t)(i + 2) * 128], a2);
            a3 = fmaf(hp[i + 3], wp[(size_t)(i + 3) * 128], a3);
        }
        red[t] = (a0 + a1) + (a2 + a3);
    }
    __syncthreads();

    if (t < 128) {
        float h2 = fmaxf(lb2[t] + red[t] + red[t + 128] + red[t + 256], 0.0f);
        red[t] = h2 * lw3[t];
    }
    __syncthreads();
    if (t < 64) {
        float sv = red[t] + red[t + 64];
        #pragma unroll
        for (int off = 32; off > 0; off >>= 1) sv += __shfl_down(sv, off, 64);
        if (t == 0) out[g] = 1.0f / (1.0f + expf(-(sv + lb3[0])));
    }
}

extern "C" void kernel_launch(void* const* d_in, const int* in_sizes, int n_in,
                              void* d_out, int out_size, void* d_ws, size_t ws_size,
                              hipStream_t stream) {
    (void)n_in; (void)ws_size;
    const float* x     = (const float*)d_in[0];
    const int*   ei    = (const int*)d_in[1];
    const int*   batch = (const int*)d_in[2];
    const float* W1  = (const float*)d_in[3];
    const float* b1  = (const float*)d_in[4];
    const float* W2  = (const float*)d_in[5];
    const float* b2  = (const float*)d_in[6];
    const float* lw1 = (const float*)d_in[7];
    const float* lb1 = (const float*)d_in[8];
    const float* lw2 = (const float*)d_in[9];
    const float* lb2 = (const float*)d_in[10];
    const float* lw3 = (const float*)d_in[11];
    const float* lb3 = (const float*)d_in[12];
    float* out = (float*)d_out;

    const int N = in_sizes[2];      // 50000 nodes (< 65536 -> uint16 ids)
    const int E = in_sizes[1] / 2;  // 800000 edges
    const int G = out_size;         // 512 graphs

    const int* src = ei;
    const int* dst = ei + E;

    size_t off = 0;
    auto alloc = [&](size_t bytes) -> void* {
        void* p = (char*)d_ws + off;
        off += (bytes + 255) & ~(size_t)255;
        return p;
    };

    f16*   hs     = (f16*)alloc((size_t)N * 128 * 2);   // gemm out (blocked)
    f16*   hb     = (f16*)alloc((size_t)N * 128 * 2);   // agg out (blocked)
    f16*   Wt1    = (f16*)alloc((size_t)128 * 128 * 2);
    f16*   Wt2    = (f16*)alloc((size_t)128 * 128 * 2);
    float* dv     = (float*)alloc((size_t)N * 4);
    int*   deg    = (int*)alloc((size_t)N * 4);
    int*   rowoff = (int*)alloc((size_t)(N + 1) * 4);
    int*   cursor = (int*)alloc((size_t)N * 4);
    unsigned short* colsrc = (unsigned short*)alloc((size_t)E * 2);
    unsigned* q   = (unsigned*)alloc((size_t)NR * QCAP * 4);
    int*   qcnt   = (int*)alloc((size_t)(NR * QPAD + NR) * 4);  // counters + rtot
    int*   goff   = (int*)alloc((size_t)(G + 1) * 4);
    int*   rtot   = qcnt + NR * QPAD;

    const int bsz = (N + NR - 1) / NR;   // 6250 <= BSZ_MAX
    const int setup_blocks = 64 + (G + 1 + 255) / 256;

    // setup first: zeros qcnt+rtot (block 0) + wcast + goff; no upstream deps
    setup_misc<<<setup_blocks, 256, 0, stream>>>(W1, W2, Wt1, Wt2, batch, N, G, goff, qcnt);
    bucket_edges<<<(E + EPB - 1) / EPB, 256, 0, stream>>>(src, dst, E, bsz, N, deg, qcnt, q);
    deg_hist_split<<<NR * DSPLIT, 256, 0, stream>>>(qcnt, q, bsz, N, deg, rtot);
    range_scan<<<NR, 1024, 0, stream>>>(deg, rtot, bsz, N, rowoff, cursor, dv);
    fill_from_buckets<<<NR * NSPLIT, 256, 0, stream>>>(qcnt, q, cursor, colsrc);

    const int gemm_blocks = (N + 63) / 64;
    const int agg_blocks  = 4 * ((N + 63) / 64);

    // layer 1 (reads fp32 x directly)
    gemm_mfma<true><<<gemm_blocks, 256, 0, stream>>>(x, Wt1, dv, hs, N);
    agg_relu_b<<<agg_blocks, 256, 0, stream>>>(hs, dv, b1, rowoff, colsrc, hb, N);
    // layer 2
    gemm_mfma<false><<<gemm_blocks, 256, 0, stream>>>(hb, Wt2, dv, hs, N);
    agg_relu_b<<<agg_blocks, 256, 0, stream>>>(hs, dv, b2, rowoff, colsrc, hb, N);
    // layer 3 (shared weights)
    gemm_mfma<false><<<gemm_blocks, 256, 0, stream>>>(hb, Wt2, dv, hs, N);
    agg_relu_b<<<agg_blocks, 256, 0, stream>>>(hs, dv, b2, rowoff, colsrc, hb, N);

    pool_mlp<<<G, 384, 0, stream>>>(hb, goff, N, lw1, lb1, lw2, lb2, lw3, lb3, out);
}

// Round 21
// 238.085 us; speedup vs baseline: 1.0325x; 1.0325x over previous
//
#include <hip/hip_runtime.h>
#include <hip/hip_bf16.h>
#include <hip/hip_fp16.h>
#include <math.h>

// ---------------------------------------------------------------------------
// GCN: 3x gcn_conv(relu) -> tri-pool per graph -> MLP head -> sigmoid
// GEMMs on matrix cores (fp16 in, fp32 acc). Node features feature-BLOCKED:
// h[fb][v][32] (fb=0..3; 64B rows = 1 cache line); aggregation blocks pinned
// to XCD (fb = blockIdx&3) gather a 3.2MB slice (per-XCD L2 resident).
// agg: lane owns 8 feats (16B f16x8), 16 nodes/wave; block's edge-index
// segment staged into LDS (index loads off the VMEM pipe); gathered rows
// summed via packed-f16 pairwise tree (v_pk_add_f16, 3x fewer VALU ops)
// with fp32 master accumulator. CSR build: 8 dst-range queues (64B-aligned,
// sentinel-padded; line-padded counters), split LDS histograms, XCD-pinned
// fill. Pool fused into MLP head. No hipMemsetAsync.
// (Round-20's fused 8-block range_scan regressed -7us: grid starvation;
// the parallel blk_reduce+scan_blocks pair is restored.)
// ---------------------------------------------------------------------------

typedef _Float16 f16;
typedef _Float16 f16x2 __attribute__((ext_vector_type(2)));
typedef _Float16 f16x4 __attribute__((ext_vector_type(4)));
typedef _Float16 f16x8 __attribute__((ext_vector_type(8)));
typedef float f32x4 __attribute__((ext_vector_type(4)));

#define NR 8          // dst ranges (one per XCD)
#define NSPLIT 32     // queue splits in fill pass
#define DSPLIT 16     // queue splits in deg-hist pass
#define QCAP 200000   // per-range queue capacity (valid ~100k + pad ~12k)
#define BSZ_MAX 6272  // max nodes per range (50000/8 = 6250, rounded up)
#define QPAD 16       // qcnt stride in ints (64B line per counter)
#define EPB 1024      // edges per block in bucket pass
#define ECAP 4096     // LDS edge-index cache per agg block (64 nodes)
#define SENTINEL 0xFFFFFFFFu

__device__ inline int wave_incl_scan(int v, int lane) {
    #pragma unroll
    for (int off = 1; off < 64; off <<= 1) {
        int nv = __shfl_up(v, off, 64);
        if (lane >= off) v += nv;
    }
    return v;
}

// Phase 1 of deg scan + dinv (single read of deg).
__global__ __launch_bounds__(256) void blk_reduce_fused(
    const int* __restrict__ deg, int n, int* __restrict__ bsum,
    float* __restrict__ dv) {
    __shared__ int ws[4];
    const int t = threadIdx.x;
    int i = blockIdx.x * 256 + t;
    int v = (i < n) ? deg[i] : 0;
    if (i < n) dv[i] = 1.0f / sqrtf((float)v + 1.0f);
    int r = v;
    #pragma unroll
    for (int off = 32; off > 0; off >>= 1) r += __shfl_down(r, off, 64);
    const int lane = t & 63, wid = t >> 6;
    if (lane == 0) ws[wid] = r;
    __syncthreads();
    if (t == 0) bsum[blockIdx.x] = ws[0] + ws[1] + ws[2] + ws[3];
}

// Phase 2: exclusive scan; out/out2[i] = prefix; out[n] = total.
__global__ __launch_bounds__(256) void scan_blocks(
    const int* __restrict__ in, int n, const int* __restrict__ bsum, int nb,
    int* __restrict__ out, int* __restrict__ out2) {
    __shared__ int ws[4];
    __shared__ int wpre[4];
    const int b = blockIdx.x, t = threadIdx.x;
    const int lane = t & 63, wid = t >> 6;

    int pv = 0;
    for (int j = t; j < b && j < nb; j += 256) pv += bsum[j];
    #pragma unroll
    for (int off = 32; off > 0; off >>= 1) pv += __shfl_down(pv, off, 64);
    if (lane == 0) ws[wid] = pv;
    __syncthreads();
    const int prefix = ws[0] + ws[1] + ws[2] + ws[3];

    const int i = b * 256 + t;
    int v = (i < n) ? in[i] : 0;
    int isc = wave_incl_scan(v, lane);
    if (lane == 63) wpre[wid] = isc;
    __syncthreads();
    int wb = 0;
    for (int w = 0; w < wid; ++w) wb += wpre[w];
    int ex = prefix + wb + isc - v;
    if (i < n) { out[i] = ex; out2[i] = ex; }
    if (i == n) out[n] = ex;
}

// CSR pass A: bucket edges into NR dst-range queues (packed dst<<16|src).
// Also zeros deg[]. 1024 edges/block (int4), ballot-aggregated LDS counters,
// ONE global atomicAdd per (block, range) on a line-padded counter.
__global__ __launch_bounds__(256) void bucket_edges(
    const int* __restrict__ src, const int* __restrict__ dst, int E, int bsz,
    int N, int* __restrict__ deg, int* __restrict__ qcnt,
    unsigned* __restrict__ q) {
    __shared__ int lcnt[NR];
    __shared__ int lbase[NR];
    const int t = threadIdx.x;
    const int lane = t & 63;

    // zero deg (50k ints over ~782 blocks: one strided pass)
    for (int i = blockIdx.x * 256 + t; i < N; i += gridDim.x * 256) deg[i] = 0;

    if (t < NR) lcnt[t] = 0;
    __syncthreads();

    const int e0 = blockIdx.x * EPB + t * 4;
    int  rj[4];
    int  lp[4];
    unsigned pk[4];
    if (e0 + 4 <= E) {
        int4 d4 = *(const int4*)(dst + e0);
        int4 s4 = *(const int4*)(src + e0);
        rj[0] = d4.x / bsz; pk[0] = ((unsigned)d4.x << 16) | (unsigned)s4.x;
        rj[1] = d4.y / bsz; pk[1] = ((unsigned)d4.y << 16) | (unsigned)s4.y;
        rj[2] = d4.z / bsz; pk[2] = ((unsigned)d4.z << 16) | (unsigned)s4.z;
        rj[3] = d4.w / bsz; pk[3] = ((unsigned)d4.w << 16) | (unsigned)s4.w;
    } else {
        #pragma unroll
        for (int j = 0; j < 4; ++j) {
            int e = e0 + j;
            if (e < E) {
                int d = dst[e];
                rj[j] = d / bsz;
                pk[j] = ((unsigned)d << 16) | (unsigned)src[e];
            } else rj[j] = -1;
        }
    }

    #pragma unroll
    for (int j = 0; j < 4; ++j) {
        #pragma unroll
        for (int rr = 0; rr < NR; ++rr) {
            bool mine = (rj[j] == rr);
            unsigned long long m = __ballot(mine);
            if (m) {
                int leader = __ffsll((long long)m) - 1;
                int base = 0;
                if (lane == leader) base = atomicAdd(&lcnt[rr], __popcll(m));
                base = __shfl(base, leader);
                if (mine) lp[j] = base + __popcll(m & ((1ull << lane) - 1ull));
            }
        }
    }
    __syncthreads();
    if (t < NR) {
        int padded = (lcnt[t] + 15) & ~15;
        lbase[t] = atomicAdd(&qcnt[t * QPAD], padded);  // padded: own 64B line
    }
    __syncthreads();
    #pragma unroll
    for (int j = 0; j < 4; ++j) {
        if (rj[j] >= 0) {
            int pos = lbase[rj[j]] + lp[j];
            if (pos < QCAP) q[(size_t)rj[j] * QCAP + pos] = pk[j];
        }
    }
    if (t < NR) {
        int base = lbase[t], c = lcnt[t], pad = (c + 15) & ~15;
        for (int i = c; i < pad; ++i)
            if (base + i < QCAP) q[(size_t)t * QCAP + base + i] = SENTINEL;
    }
}

// CSR pass B1: split per-range degree histograms (grid = NR * DSPLIT).
__global__ __launch_bounds__(256) void deg_hist_split(
    const int* __restrict__ qcnt, const unsigned* __restrict__ q,
    int bsz, int N, int* __restrict__ deg) {
    __shared__ int hist[BSZ_MAX];
    const int r = blockIdx.x & (NR - 1);
    const int sp = blockIdx.x >> 3;
    const int lo = r * bsz;
    const int hi = min(lo + bsz, N);
    const int span = hi - lo;
    const int t = threadIdx.x;
    for (int i = t; i < span; i += 256) hist[i] = 0;
    __syncthreads();
    const int qn = min(qcnt[r * QPAD], QCAP);
    const int i0 = (int)((long long)qn * sp / DSPLIT);
    const int i1 = (int)((long long)qn * (sp + 1) / DSPLIT);
    const unsigned* qr = q + (size_t)r * QCAP;
    for (int i = i0 + t; i < i1; i += 256) {
        unsigned u = qr[i];
        if (u != SENTINEL) atomicAdd(&hist[(int)(u >> 16) - lo], 1);
    }
    __syncthreads();
    for (int i = t; i < span; i += 256) {
        int c = hist[i];
        if (c) atomicAdd(&deg[lo + i], c);
    }
}

// CSR pass B2: drain queue r = blockIdx&7 (XCD-pinned) -> colsrc scatter
// writes for range r stay in ONE L2.
__global__ __launch_bounds__(256) void fill_from_buckets(
    const int* __restrict__ qcnt, const unsigned* __restrict__ q,
    int* __restrict__ cursor, unsigned short* __restrict__ colsrc) {
    const int r = blockIdx.x & (NR - 1);
    const int sp = blockIdx.x >> 3;
    const int n = min(qcnt[r * QPAD], QCAP);
    const int i0 = (int)((long long)n * sp / NSPLIT);
    const int i1 = (int)((long long)n * (sp + 1) / NSPLIT);
    for (int i = i0 + threadIdx.x; i < i1; i += 256) {
        unsigned u = q[(size_t)r * QCAP + i];
        if (u == SENTINEL) continue;
        int d = u >> 16;
        int p = atomicAdd(&cursor[d], 1);
        colsrc[p] = (unsigned short)(u & 0xffffu);
    }
}

// Fused setup (launched FIRST): blocks 0..63 -> wcast; block 0 also zeros
// qcnt; blocks 64.. -> goff[g] = lower_bound(batch, g).
__global__ __launch_bounds__(256) void setup_misc(
    const float* __restrict__ W1, const float* __restrict__ W2,
    f16* __restrict__ Wt1, f16* __restrict__ Wt2,
    const int* __restrict__ batch, int N, int G, int* __restrict__ goff,
    int* __restrict__ qcnt) {
    const int b = blockIdx.x;
    if (b < 64) {
        if (b == 0 && threadIdx.x < NR * QPAD) qcnt[threadIdx.x] = 0;
        int idx = b * 256 + threadIdx.x;  // 0..16383
        int n = idx >> 7, k = idx & 127;
        Wt1[idx] = (f16)W1[k * 128 + n];
        Wt2[idx] = (f16)W2[k * 128 + n];
    } else {
        int g = (b - 64) * 256 + threadIdx.x;
        if (g > G) return;
        int lo = 0, hi = N;
        while (lo < hi) {
            int mid = (lo + hi) >> 1;
            if (batch[mid] < g) lo = mid + 1; else hi = mid;
        }
        goff[g] = lo;
    }
}

// out[fb][m][32] = fp16((A[m][:] @ W) * dv[m])
// F32IN: A row-major fp32 [M][128] (input x); else blocked fp16 [fb][m][32].
// MFMA 16x16x32_f16, D[n][m]: lane's 4 acc regs = 4 consecutive n at one m.
template <bool F32IN>
__global__ __launch_bounds__(256) void gemm_mfma(
    const void* __restrict__ Ain, const f16* __restrict__ Wt,
    const float* __restrict__ dv, f16* __restrict__ out, int M) {
    const int lane = threadIdx.x & 63;
    const int w = threadIdx.x >> 6;
    const int wc = w & 1;
    const int wr = w >> 1;
    const int l15 = lane & 15;
    const int lg = lane >> 4;  // 0..3

    // Hoist Wt fragments (MFMA A-operand): A_op[n][k], n = l15, k = lg*8+j
    f16x8 wf[4][4];  // [nt][kb]
    #pragma unroll
    for (int nt = 0; nt < 4; ++nt) {
        const f16* wp = Wt + (size_t)(wc * 64 + nt * 16 + l15) * 128 + lg * 8;
        #pragma unroll
        for (int kb = 0; kb < 4; ++kb)
            wf[nt][kb] = *(const f16x8*)(wp + kb * 32);
    }

    #pragma unroll
    for (int step = 0; step < 2; ++step) {
        const int m = blockIdx.x * 64 + step * 32 + wr * 16 + l15;
        const int mc = min(m, M - 1);
        // B-operand: k = kb*32 + lg*8 + j  ->  block kb, offset lg*8
        f16x8 af[4];
        if constexpr (F32IN) {
            const float* ap = (const float*)Ain + (size_t)mc * 128 + lg * 8;
            #pragma unroll
            for (int kb = 0; kb < 4; ++kb) {
                float4 a = *(const float4*)(ap + kb * 32);
                float4 b = *(const float4*)(ap + kb * 32 + 4);
                f16x8 o;
                o[0] = (f16)a.x; o[1] = (f16)a.y; o[2] = (f16)a.z; o[3] = (f16)a.w;
                o[4] = (f16)b.x; o[5] = (f16)b.y; o[6] = (f16)b.z; o[7] = (f16)b.w;
                af[kb] = o;
            }
        } else {
            const f16* A = (const f16*)Ain;
            #pragma unroll
            for (int kb = 0; kb < 4; ++kb)
                af[kb] = *(const f16x8*)(A + ((size_t)kb * M + mc) * 32 + lg * 8);
        }
        const float d = dv[mc];
        #pragma unroll
        for (int nt = 0; nt < 4; ++nt) {
            f32x4 acc = {0.f, 0.f, 0.f, 0.f};
            #pragma unroll
            for (int kb = 0; kb < 4; ++kb)
                acc = __builtin_amdgcn_mfma_f32_16x16x32_f16(wf[nt][kb], af[kb], acc, 0, 0, 0);
            if (m < M) {
                // n = wc*64 + nt*16 + lg*4 + j -> fb = wc*2+(nt>>1), off = (nt&1)*16+lg*4
                f16x4 o;
                o[0] = (f16)(acc[0] * d);
                o[1] = (f16)(acc[1] * d);
                o[2] = (f16)(acc[2] * d);
                o[3] = (f16)(acc[3] * d);
                *(f16x4*)(out + ((size_t)(wc * 2 + (nt >> 1)) * M + m) * 32
                          + (nt & 1) * 16 + lg * 4) = o;
            }
        }
    }
}

// Feature-blocked aggregation, 4 fb x 32 feats (64B rows). Block handles
// fb = blockIdx&3 (XCD-pinned slice, L2-resident) and 64 nodes; edge-index
// segment staged in LDS. Wave = 16 node-slots x 4 lanes; lane owns 8 feats
// (f16x8, 16B). Gathered rows reduced via packed-f16 pairwise tree
// (v_pk_add_f16; ~3x fewer VALU ops than per-element cvt+add) into a fp32
// master accumulator once per 8-edge group.
__global__ __launch_bounds__(256) void agg_relu_b(
    const f16* __restrict__ hs, const float* __restrict__ dv,
    const float* __restrict__ bias, const int* __restrict__ rowoff,
    const unsigned short* __restrict__ colsrc, f16* __restrict__ out, int N) {
    __shared__ unsigned short ecache[ECAP];
    const int fb = blockIdx.x & 3;
    const int chunk = blockIdx.x >> 2;
    const int t = threadIdx.x;
    const int lane = t & 63;
    const int wav = t >> 6;
    const int sl = lane & 3;       // feature octet within row
    const int slot = lane >> 2;    // node slot within wave (16)
    const int vb0 = chunk * 64;
    const int v = vb0 + wav * 16 + slot;

    // stage the block's edge-index segment (all threads participate)
    const int vend = min(vb0 + 64, N);
    const int E0 = rowoff[vb0];
    const int E1 = rowoff[vend];
    const int nE = E1 - E0;
    const bool staged = (nE <= ECAP);
    if (staged) {
        for (int i = t; i < nE; i += 256) ecache[i] = colsrc[E0 + i];
    }
    __syncthreads();

    if (v >= N) return;

    const f16* slice = hs + (size_t)fb * N * 32;
    f16x8 h0 = *(const f16x8*)(slice + (size_t)v * 32 + sl * 8);
    float a0 = (float)h0[0], a1 = (float)h0[1], a2 = (float)h0[2], a3 = (float)h0[3];
    float a4 = (float)h0[4], a5 = (float)h0[5], a6 = (float)h0[6], a7 = (float)h0[7];

    const int e0 = rowoff[v], e1 = rowoff[v + 1];
    if (staged) {
        int eiter = e0 - E0;
        const int ee = e1 - E0;
        for (; eiter + 8 <= ee; eiter += 8) {
            int s[8];
            #pragma unroll
            for (int j = 0; j < 8; ++j) s[j] = ecache[eiter + j];
            f16x8 m[8];
            #pragma unroll
            for (int j = 0; j < 8; ++j)
                m[j] = *(const f16x8*)(slice + (size_t)s[j] * 32 + sl * 8);
            // packed-f16 pairwise tree, then one fp32 accumulate
            f16x8 t01 = m[0] + m[1];
            f16x8 t23 = m[2] + m[3];
            f16x8 t45 = m[4] + m[5];
            f16x8 t67 = m[6] + m[7];
            f16x8 tt = (t01 + t23) + (t45 + t67);
            a0 += (float)tt[0]; a1 += (float)tt[1];
            a2 += (float)tt[2]; a3 += (float)tt[3];
            a4 += (float)tt[4]; a5 += (float)tt[5];
            a6 += (float)tt[6]; a7 += (float)tt[7];
        }
        for (; eiter < ee; ++eiter) {
            int s = ecache[eiter];
            f16x8 mm = *(const f16x8*)(slice + (size_t)s * 32 + sl * 8);
            a0 += (float)mm[0]; a1 += (float)mm[1];
            a2 += (float)mm[2]; a3 += (float)mm[3];
            a4 += (float)mm[4]; a5 += (float)mm[5];
            a6 += (float)mm[6]; a7 += (float)mm[7];
        }
    } else {
        int e = e0;
        for (; e + 8 <= e1; e += 8) {
            int s[8];
            #pragma unroll
            for (int j = 0; j < 8; ++j) s[j] = colsrc[e + j];
            f16x8 m[8];
            #pragma unroll
            for (int j = 0; j < 8; ++j)
                m[j] = *(const f16x8*)(slice + (size_t)s[j] * 32 + sl * 8);
            f16x8 t01 = m[0] + m[1];
            f16x8 t23 = m[2] + m[3];
            f16x8 t45 = m[4] + m[5];
            f16x8 t67 = m[6] + m[7];
            f16x8 tt = (t01 + t23) + (t45 + t67);
            a0 += (float)tt[0]; a1 += (float)tt[1];
            a2 += (float)tt[2]; a3 += (float)tt[3];
            a4 += (float)tt[4]; a5 += (float)tt[5];
            a6 += (float)tt[6]; a7 += (float)tt[7];
        }
        for (; e < e1; ++e) {
            int s = colsrc[e];
            f16x8 mm = *(const f16x8*)(slice + (size_t)s * 32 + sl * 8);
            a0 += (float)mm[0]; a1 += (float)mm[1];
            a2 += (float)mm[2]; a3 += (float)mm[3];
            a4 += (float)mm[4]; a5 += (float)mm[5];
            a6 += (float)mm[6]; a7 += (float)mm[7];
        }
    }

    float d = dv[v];
    const float* bp = bias + fb * 32 + sl * 8;
    float4 b0 = *(const float4*)bp;
    float4 b1 = *(const float4*)(bp + 4);
    f16x8 o;
    o[0] = (f16)fmaxf(fmaf(d, a0, b0.x), 0.0f);
    o[1] = (f16)fmaxf(fmaf(d, a1, b0.y), 0.0f);
    o[2] = (f16)fmaxf(fmaf(d, a2, b0.z), 0.0f);
    o[3] = (f16)fmaxf(fmaf(d, a3, b0.w), 0.0f);
    o[4] = (f16)fmaxf(fmaf(d, a4, b1.x), 0.0f);
    o[5] = (f16)fmaxf(fmaf(d, a5, b1.y), 0.0f);
    o[6] = (f16)fmaxf(fmaf(d, a6, b1.z), 0.0f);
    o[7] = (f16)fmaxf(fmaf(d, a7, b1.w), 0.0f);
    *(f16x8*)(out + ((size_t)fb * N + v) * 32 + sl * 8) = o;
}

// Fused tri-pool + MLP head. One block (384 threads) per graph.
__global__ __launch_bounds__(384) void pool_mlp(
    const f16* __restrict__ h, const int* __restrict__ goff, int N,
    const float* __restrict__ lw1, const float* __restrict__ lb1,
    const float* __restrict__ lw2, const float* __restrict__ lb2,
    const float* __restrict__ lw3, const float* __restrict__ lb3,
    float* __restrict__ out) {
    __shared__ float psum[3][128];
    __shared__ float pmax[3][128];
    __shared__ float gin[384];
    __shared__ float h1[384];
    __shared__ float red[384];
    const int g = blockIdx.x, t = threadIdx.x;
    const int s = goff[g], e = goff[g + 1];

    {   // pool: group c = t>>7 strides the node range for feature f = t&127
        const int c = t >> 7, f = t & 127;
        const int fb = f >> 5, off = f & 31;
        const f16* slice = h + ((size_t)fb * N) * 32 + off;
        float sum = 0.0f, mx = 0.0f;  // h >= 0 post-relu
        for (int v = s + c; v < e; v += 3) {
            float val = (float)slice[(size_t)v * 32];
            sum += val;
            mx = fmaxf(mx, val);
        }
        psum[c][f] = sum;
        pmax[c][f] = mx;
    }
    __syncthreads();
    if (t < 128) {
        float ts = psum[0][t] + psum[1][t] + psum[2][t];
        float tm = fmaxf(fmaxf(pmax[0][t], pmax[1][t]), pmax[2][t]);
        float cnt = (float)(e - s);
        gin[t]       = ts / fmaxf(cnt, 1.0f);  // pmean (empty graph -> 0)
        gin[128 + t] = tm;                     // pmax
        gin[256 + t] = ts;                     // psum
    }
    __syncthreads();

    {   // layer 1: h1[t] = relu(lb1[t] + sum_i gin[i] * lw1[i][t])
        const float* wp = lw1 + t;
        float a0 = 0.f, a1 = 0.f, a2 = 0.f, a3 = 0.f;
        for (int i = 0; i < 384; i += 4) {
            a0 = fmaf(gin[i],     wp[(size_t)i * 384],        a0);
            a1 = fmaf(gin[i + 1], wp[(size_t)(i + 1) * 384],  a1);
            a2 = fmaf(gin[i + 2], wp[(size_t)(i + 2) * 384],  a2);
            a3 = fmaf(gin[i + 3], wp[(size_t)(i + 3) * 384],  a3);
        }
        h1[t] = fmaxf(lb1[t] + (a0 + a1) + (a2 + a3), 0.0f);
    }
    __syncthreads();

    {   // layer 2: partial over k-chunk (t>>7) for col (t&127)
        const int jj = t & 127, chunk = t >> 7;
        const float* wp = lw2 + (size_t)chunk * 128 * 128 + jj;
        const float* hp = h1 + chunk * 128;
        float a0 = 0.f, a1 = 0.f, a2 = 0.f, a3 = 0.f;
        for (int i = 0; i < 128; i += 4) {
            a0 = fmaf(hp[i],     wp[(size_t)i * 128],       a0);
            a1 = fmaf(hp[i + 1], wp[(size_t)(i + 1) * 128], a1);
            a2 = fmaf(hp[i + 2], wp[(size_t)(i + 2) * 128], a2);
            a3 = fmaf(hp[i + 3], wp[(size_t)(i + 3) * 128], a3);
        }
        red[t] = (a0 + a1) + (a2 + a3);
    }
    __syncthreads();

    if (t < 128) {
        float h2 = fmaxf(lb2[t] + red[t] + red[t + 128] + red[t + 256], 0.0f);
        red[t] = h2 * lw3[t];
    }
    __syncthreads();
    if (t < 64) {
        float sv = red[t] + red[t + 64];
        #pragma unroll
        for (int off = 32; off > 0; off >>= 1) sv += __shfl_down(sv, off, 64);
        if (t == 0) out[g] = 1.0f / (1.0f + expf(-(sv + lb3[0])));
    }
}

extern "C" void kernel_launch(void* const* d_in, const int* in_sizes, int n_in,
                              void* d_out, int out_size, void* d_ws, size_t ws_size,
                              hipStream_t stream) {
    (void)n_in; (void)ws_size;
    const float* x     = (const float*)d_in[0];
    const int*   ei    = (const int*)d_in[1];
    const int*   batch = (const int*)d_in[2];
    const float* W1  = (const float*)d_in[3];
    const float* b1  = (const float*)d_in[4];
    const float* W2  = (const float*)d_in[5];
    const float* b2  = (const float*)d_in[6];
    const float* lw1 = (const float*)d_in[7];
    const float* lb1 = (const float*)d_in[8];
    const float* lw2 = (const float*)d_in[9];
    const float* lb2 = (const float*)d_in[10];
    const float* lw3 = (const float*)d_in[11];
    const float* lb3 = (const float*)d_in[12];
    float* out = (float*)d_out;

    const int N = in_sizes[2];      // 50000 nodes (< 65536 -> uint16 ids)
    const int E = in_sizes[1] / 2;  // 800000 edges
    const int G = out_size;         // 512 graphs

    const int* src = ei;
    const int* dst = ei + E;

    size_t off = 0;
    auto alloc = [&](size_t bytes) -> void* {
        void* p = (char*)d_ws + off;
        off += (bytes + 255) & ~(size_t)255;
        return p;
    };
    const int nb = (N + 255) / 256;

    f16*   hs     = (f16*)alloc((size_t)N * 128 * 2);   // gemm out (blocked)
    f16*   hb     = (f16*)alloc((size_t)N * 128 * 2);   // agg out (blocked)
    f16*   Wt1    = (f16*)alloc((size_t)128 * 128 * 2);
    f16*   Wt2    = (f16*)alloc((size_t)128 * 128 * 2);
    float* dv     = (float*)alloc((size_t)N * 4);
    int*   deg    = (int*)alloc((size_t)N * 4);
    int*   rowoff = (int*)alloc((size_t)(N + 1) * 4);
    int*   cursor = (int*)alloc((size_t)N * 4);
    int*   bsum   = (int*)alloc((size_t)nb * 4);
    unsigned short* colsrc = (unsigned short*)alloc((size_t)E * 2);
    unsigned* q   = (unsigned*)alloc((size_t)NR * QCAP * 4);
    int*   qcnt   = (int*)alloc((size_t)NR * QPAD * 4);  // line-padded counters
    int*   goff   = (int*)alloc((size_t)(G + 1) * 4);

    const int nscan = (N + 1 + 255) / 256;
    const int bsz = (N + NR - 1) / NR;   // 6250 <= BSZ_MAX
    const int setup_blocks = 64 + (G + 1 + 255) / 256;

    // setup first: zeros qcnt (block 0) + wcast + goff; no upstream deps
    setup_misc<<<setup_blocks, 256, 0, stream>>>(W1, W2, Wt1, Wt2, batch, N, G, goff, qcnt);
    bucket_edges<<<(E + EPB - 1) / EPB, 256, 0, stream>>>(src, dst, E, bsz, N, deg, qcnt, q);
    deg_hist_split<<<NR * DSPLIT, 256, 0, stream>>>(qcnt, q, bsz, N, deg);
    blk_reduce_fused<<<nb, 256, 0, stream>>>(deg, N, bsum, dv);
    scan_blocks<<<nscan, 256, 0, stream>>>(deg, N, bsum, nb, rowoff, cursor);
    fill_from_buckets<<<NR * NSPLIT, 256, 0, stream>>>(qcnt, q, cursor, colsrc);

    const int gemm_blocks = (N + 63) / 64;
    const int agg_blocks  = 4 * ((N + 63) / 64);

    // layer 1 (reads fp32 x directly)
    gemm_mfma<true><<<gemm_blocks, 256, 0, stream>>>(x, Wt1, dv, hs, N);
    agg_relu_b<<<agg_blocks, 256, 0, stream>>>(hs, dv, b1, rowoff, colsrc, hb, N);
    // layer 2
    gemm_mfma<false><<<gemm_blocks, 256, 0, stream>>>(hb, Wt2, dv, hs, N);
    agg_relu_b<<<agg_blocks, 256, 0, stream>>>(hs, dv, b2, rowoff, colsrc, hb, N);
    // layer 3 (shared weights)
    gemm_mfma<false><<<gemm_blocks, 256, 0, stream>>>(hb, Wt2, dv, hs, N);
    agg_relu_b<<<agg_blocks, 256, 0, stream>>>(hs, dv, b2, rowoff, colsrc, hb, N);

    pool_mlp<<<G, 384, 0, stream>>>(hb, goff, N, lw1, lb1, lw2, lb2, lw3, lb3, out);
}